// Round 4
// baseline (350.077 us; speedup 1.0000x reference)
//
#include <hip/hip_runtime.h>

#define HWp 65536   // 256*256 pixels per plane
#define Wd  256
#define Hd  256

__device__ __forceinline__ float fast_tanh(float v) {
    // tanh(v) = 1 - 2/(exp(2v)+1); exp overflow/underflow saturate correctly
    return 1.0f - 2.0f / (__expf(2.0f * v) + 1.0f);
}

// ---------------------------------------------------------------------------
// K1: strip-pool x.  One block per (b,c) plane.
//   Sh[b,c,w] = mean_h x[b,c,h,w]   Sv[b,c,h] = mean_w x[b,c,h,w]
// ---------------------------------------------------------------------------
__global__ __launch_bounds__(256) void k_pool(const float* __restrict__ x,
                                              float* __restrict__ Sh,
                                              float* __restrict__ Sv) {
    const int bc = blockIdx.x;                 // b*64+c
    const float* plane = x + (size_t)bc * HWp;
    const int t  = threadIdx.x;
    const int w4 = t & 63;                     // column group (4 cols)
    const int hg = t >> 6;                     // wave id -> row range
    __shared__ float rowsum[256];
    __shared__ float colpart[4 * 256];

    float4 cacc = make_float4(0.f, 0.f, 0.f, 0.f);
    #pragma unroll 4
    for (int hh = 0; hh < 64; ++hh) {
        const int h = hg * 64 + hh;
        const float4 v = *reinterpret_cast<const float4*>(plane + h * Wd + w4 * 4);
        cacc.x += v.x; cacc.y += v.y; cacc.z += v.z; cacc.w += v.w;
        float rs = v.x + v.y + v.z + v.w;
        #pragma unroll
        for (int m = 32; m; m >>= 1) rs += __shfl_xor(rs, m, 64);
        if (w4 == 0) rowsum[h] = rs;           // each row owned by exactly one wave
    }
    *reinterpret_cast<float4*>(&colpart[hg * 256 + w4 * 4]) = cacc;
    __syncthreads();

    Sv[bc * 256 + t] = rowsum[t] * (1.0f / 256.0f);
    const float cs = colpart[t] + colpart[256 + t] + colpart[512 + t] + colpart[768 + t];
    Sh[bc * 256 + t] = cs * (1.0f / 256.0f);
}

// ---------------------------------------------------------------------------
// K2a: 1x1 conv (+bias) on the pooled strips (pool commutes with 1x1 conv).
//   PH[b,o,w] = sum_c cw[o,c]*Sh[b,c,w] + cb[o]   (and PV from Sv)
// ---------------------------------------------------------------------------
__global__ __launch_bounds__(256) void k_conv1(const float* __restrict__ Sh,
                                               const float* __restrict__ Sv,
                                               const float* __restrict__ cw,
                                               const float* __restrict__ cb,
                                               float* __restrict__ PH,
                                               float* __restrict__ PV) {
    const int flat = blockIdx.x * 256 + threadIdx.x;
    const int w    = flat & 255;
    const int o    = (flat >> 8) & 63;         // uniform within block
    const int b    = (flat >> 14) & 3;
    const int half = flat >> 16;
    const float* src = half ? Sv : Sh;
    float*       dst = half ? PV : PH;
    float acc = cb[o];
    #pragma unroll 16
    for (int c = 0; c < 64; ++c)
        acc += cw[o * 64 + c] * src[(b * 64 + c) * 256 + w];
    dst[(b * 64 + o) * 256 + w] = acc;
}

// ---------------------------------------------------------------------------
// K2b: length-3 conv (cross-correlation, zero pad 1) along the strip axis.
//   XH[b,o,w] = sum_c sum_j chw[o,c,j] * PH[b,c,w-1+j]   (and XV from PV/cvw)
// ---------------------------------------------------------------------------
__global__ __launch_bounds__(256) void k_conv3(const float* __restrict__ PH,
                                               const float* __restrict__ PV,
                                               const float* __restrict__ chw,
                                               const float* __restrict__ cvw,
                                               float* __restrict__ XH,
                                               float* __restrict__ XV) {
    const int flat = blockIdx.x * 256 + threadIdx.x;
    const int w    = flat & 255;
    const int o    = (flat >> 8) & 63;
    const int b    = (flat >> 14) & 3;
    const int half = flat >> 16;
    const float* src = half ? PV : PH;
    const float* wt  = half ? cvw : chw;
    float*       dst = half ? XV : XH;
    float acc = 0.f;
    #pragma unroll 8
    for (int c = 0; c < 64; ++c) {
        const float* sp = src + (b * 64 + c) * 256;
        const float* wp = wt + o * 192 + c * 3;
        const float v0 = (w >= 1)   ? sp[w - 1] : 0.f;
        const float v1 = sp[w];
        const float v2 = (w <= 254) ? sp[w + 1] : 0.f;
        acc += wp[0] * v0 + wp[1] * v1 + wp[2] * v2;
    }
    dst[(b * 64 + o) * 256 + w] = acc;
}

// ---------------------------------------------------------------------------
// K3: fully fused main kernel.  Per-pixel kernel prediction + per-pixel 3x3
// conv commuted through the 1x1 conv:
//   out[o] = sum_c W[o,c] * z[c]  +  cb[o] * kin
//   z[c]   = sum_{ij in-bounds} kern_ij * x[c, h+i-1, w+j-1]
//   kin    = sum_{ij in-bounds} kern_ij
// No 64MB y intermediate, no second pass over a big tensor.
// Block: 256 threads, tile = 128 pixels (half a row). LDS 53KB -> 3 blocks/CU.
// ---------------------------------------------------------------------------
__global__ __launch_bounds__(256) void k_fused(const float* __restrict__ x,
                                               const float* __restrict__ cw,
                                               const float* __restrict__ cb,
                                               const float* __restrict__ XH,
                                               const float* __restrict__ XV,
                                               const float* __restrict__ fw,
                                               const float* __restrict__ fb,
                                               float* __restrict__ out) {
    __shared__ __align__(16) float zl[64 * 128];     // 32KB  z[c][px]
    __shared__ __align__(16) float wt[64 * 64];      // 16KB  wt[c][o] = cw[o][c]
    __shared__ __align__(16) float kernl[9 * 128];   // 4.5KB kern[q][px]
    __shared__ __align__(16) float kinl[128];        // 0.5KB

    const int blk  = blockIdx.x;                     // [b(4)][h(256)][half(2)]
    const int half = blk & 1;
    const int h    = (blk >> 1) & 255;               // uniform in block
    const int b    = blk >> 9;
    const int w0   = half * 128;
    const int tid  = threadIdx.x;

    // stage W^T: wt[c*64+o] = cw[o*64+c]
    #pragma unroll
    for (int r = 0; r < 16; ++r) {
        const int idx = r * 256 + tid;
        wt[idx] = cw[(idx & 63) * 64 + (idx >> 6)];
    }

    // ---- phase 0: per-pixel 9-tap kernel from strip features ----
    if (tid < 128) {
        const int w = w0 + tid;
        float k9[9];
        #pragma unroll
        for (int o = 0; o < 9; ++o) k9[o] = fb[o];
        const float* XHb = XH + b * 64 * 256;
        const float* XVb = XV + b * 64 * 256;
        #pragma unroll 8
        for (int c = 0; c < 64; ++c) {
            const float s = XHb[c * 256 + w] + XVb[c * 256 + h];
            const float a = s > 0.f ? s : 0.2f * s;
            #pragma unroll
            for (int o = 0; o < 9; ++o) k9[o] += fw[o * 64 + c] * a;
        }
        float kt[9];
        #pragma unroll
        for (int o = 0; o < 9; ++o) {
            kt[o] = fast_tanh(k9[o]);
            kernl[o * 128 + tid] = kt[o];
        }
        // kin = sum of in-bounds taps
        const float m0 = (w >= 1)   ? 1.f : 0.f;
        const float m2 = (w <= 254) ? 1.f : 0.f;
        const float r0 = (h >= 1)   ? 1.f : 0.f;
        const float r2 = (h <= 254) ? 1.f : 0.f;
        float kin = 0.f;
        kin += r0 * (kt[0] * m0 + kt[1] + kt[2] * m2);
        kin +=      (kt[3] * m0 + kt[4] + kt[5] * m2);
        kin += r2 * (kt[6] * m0 + kt[7] + kt[8] * m2);
        kinl[tid] = kin;
    }
    __syncthreads();

    // ---- phase 1: z[c][px] into LDS.  2 threads per pixel (channel halves) ----
    {
        const int px = tid & 127;
        const int w  = w0 + px;
        const int cbase = (tid >> 7) * 32;
        const float* xb = x + (size_t)b * 64 * HWp;
        float kr[9];
        #pragma unroll
        for (int q = 0; q < 9; ++q) kr[q] = kernl[q * 128 + px];
        const int   wc0 = (w >= 1)   ? w - 1 : 0;
        const int   wc2 = (w <= 254) ? w + 1 : 255;
        const float m0  = (w >= 1)   ? 1.f : 0.f;
        const float m2  = (w <= 254) ? 1.f : 0.f;
        const bool  r0  = (h >= 1);              // uniform branches
        const bool  r2  = (h <= 254);
        #pragma unroll 4
        for (int cc = 0; cc < 32; ++cc) {
            const int c = cbase + cc;
            const float* cp = xb + (size_t)c * HWp;
            const float* rp1 = cp + h * 256;
            float zc = kr[3] * rp1[wc0] * m0 + kr[4] * rp1[w] + kr[5] * rp1[wc2] * m2;
            if (r0) {
                const float* rp0 = cp + (h - 1) * 256;
                zc += kr[0] * rp0[wc0] * m0 + kr[1] * rp0[w] + kr[2] * rp0[wc2] * m2;
            }
            if (r2) {
                const float* rp2 = cp + (h + 1) * 256;
                zc += kr[6] * rp2[wc0] * m0 + kr[7] * rp2[w] + kr[8] * rp2[wc2] * m2;
            }
            zl[c * 128 + px] = zc;
        }
    }
    __syncthreads();

    // ---- phase 2: out[o] = W.z + cb[o]*kin  (register-tiled GEMM) ----
    const int og = tid >> 6;                     // wave-uniform output group
    const int po = tid & 63;                     // lane -> 2 pixels
    const int o0 = og * 16;
    float2 acc[16];
    #pragma unroll
    for (int i = 0; i < 16; ++i) acc[i] = make_float2(0.f, 0.f);

    for (int c = 0; c < 64; ++c) {
        const float2 xv = *reinterpret_cast<const float2*>(&zl[c * 128 + po * 2]);
        const float4 q0 = *reinterpret_cast<const float4*>(&wt[c * 64 + o0]);
        const float4 q1 = *reinterpret_cast<const float4*>(&wt[c * 64 + o0 + 4]);
        const float4 q2 = *reinterpret_cast<const float4*>(&wt[c * 64 + o0 + 8]);
        const float4 q3 = *reinterpret_cast<const float4*>(&wt[c * 64 + o0 + 12]);
        const float ws[16] = {q0.x, q0.y, q0.z, q0.w, q1.x, q1.y, q1.z, q1.w,
                              q2.x, q2.y, q2.z, q2.w, q3.x, q3.y, q3.z, q3.w};
        #pragma unroll
        for (int i = 0; i < 16; ++i) {
            acc[i].x += ws[i] * xv.x;
            acc[i].y += ws[i] * xv.y;
        }
    }

    const float2 kin2 = *reinterpret_cast<const float2*>(&kinl[po * 2]);
    float* ob = out + (size_t)b * 64 * HWp + h * 256 + w0;
    #pragma unroll
    for (int i = 0; i < 16; ++i) {
        const float bias = cb[o0 + i];
        float2 r;
        r.x = acc[i].x + bias * kin2.x;
        r.y = acc[i].y + bias * kin2.y;
        *reinterpret_cast<float2*>(ob + (size_t)(o0 + i) * HWp + po * 2) = r;
    }
}

// ---------------------------------------------------------------------------
extern "C" void kernel_launch(void* const* d_in, const int* in_sizes, int n_in,
                              void* d_out, int out_size, void* d_ws, size_t ws_size,
                              hipStream_t stream) {
    const float* x   = (const float*)d_in[0];
    const float* cw  = (const float*)d_in[1];   // (64,64)
    const float* cb  = (const float*)d_in[2];   // (64,)
    const float* chw = (const float*)d_in[3];   // (64,64,1,3)
    const float* cvw = (const float*)d_in[4];   // (64,64,3,1)
    const float* fw  = (const float*)d_in[5];   // (9,64)
    const float* fb  = (const float*)d_in[6];   // (9,)
    float* out = (float*)d_out;

    // workspace (floats): Sh | Sv | PH | PV | XH | XV  (65536 each = 1.5MB)
    float* ws = (float*)d_ws;
    float* Sh  = ws;
    float* Sv  = Sh + 65536;
    float* PH  = Sv + 65536;
    float* PV  = PH + 65536;
    float* XHa = PV + 65536;
    float* XVa = XHa + 65536;

    hipLaunchKernelGGL(k_pool,  dim3(256),  dim3(256), 0, stream, x, Sh, Sv);
    hipLaunchKernelGGL(k_conv1, dim3(512),  dim3(256), 0, stream, Sh, Sv, cw, cb, PH, PV);
    hipLaunchKernelGGL(k_conv3, dim3(512),  dim3(256), 0, stream, PH, PV, chw, cvw, XHa, XVa);
    hipLaunchKernelGGL(k_fused, dim3(2048), dim3(256), 0, stream, x, cw, cb, XHa, XVa, fw, fb, out);
}

// Round 6
// 262.080 us; speedup vs baseline: 1.3358x; 1.3358x over previous
//
#include <hip/hip_runtime.h>

#define HWp 65536   // 256*256 pixels per plane
#define Wd  256
#define Hd  256

__device__ __forceinline__ float fast_tanh(float v) {
    // tanh(v) = 1 - 2/(exp(2v)+1); exp overflow/underflow saturate correctly
    return 1.0f - 2.0f / (__expf(2.0f * v) + 1.0f);
}

// ---------------------------------------------------------------------------
// K1: strip-pool x.  One block per (b,c) plane.
// ---------------------------------------------------------------------------
__global__ __launch_bounds__(256) void k_pool(const float* __restrict__ x,
                                              float* __restrict__ Sh,
                                              float* __restrict__ Sv) {
    const int bc = blockIdx.x;                 // b*64+c
    const float* plane = x + (size_t)bc * HWp;
    const int t  = threadIdx.x;
    const int w4 = t & 63;                     // column group (4 cols)
    const int hg = t >> 6;                     // wave id -> row range
    __shared__ float rowsum[256];
    __shared__ float colpart[4 * 256];

    float4 cacc = make_float4(0.f, 0.f, 0.f, 0.f);
    #pragma unroll 4
    for (int hh = 0; hh < 64; ++hh) {
        const int h = hg * 64 + hh;
        const float4 v = *reinterpret_cast<const float4*>(plane + h * Wd + w4 * 4);
        cacc.x += v.x; cacc.y += v.y; cacc.z += v.z; cacc.w += v.w;
        float rs = v.x + v.y + v.z + v.w;
        #pragma unroll
        for (int m = 32; m; m >>= 1) rs += __shfl_xor(rs, m, 64);
        if (w4 == 0) rowsum[h] = rs;
    }
    *reinterpret_cast<float4*>(&colpart[hg * 256 + w4 * 4]) = cacc;
    __syncthreads();

    Sv[bc * 256 + t] = rowsum[t] * (1.0f / 256.0f);
    const float cs = colpart[t] + colpart[256 + t] + colpart[512 + t] + colpart[768 + t];
    Sh[bc * 256 + t] = cs * (1.0f / 256.0f);
}

// ---------------------------------------------------------------------------
// K2a: 1x1 conv (+bias) on the pooled strips.
// ---------------------------------------------------------------------------
__global__ __launch_bounds__(256) void k_conv1(const float* __restrict__ Sh,
                                               const float* __restrict__ Sv,
                                               const float* __restrict__ cw,
                                               const float* __restrict__ cb,
                                               float* __restrict__ PH,
                                               float* __restrict__ PV) {
    const int flat = blockIdx.x * 256 + threadIdx.x;
    const int w    = flat & 255;
    const int o    = (flat >> 8) & 63;         // uniform within block
    const int b    = (flat >> 14) & 3;
    const int half = flat >> 16;
    const float* src = half ? Sv : Sh;
    float*       dst = half ? PV : PH;
    float acc = cb[o];
    #pragma unroll 16
    for (int c = 0; c < 64; ++c)
        acc += cw[o * 64 + c] * src[(b * 64 + c) * 256 + w];
    dst[(b * 64 + o) * 256 + w] = acc;
}

// ---------------------------------------------------------------------------
// K2b: length-3 conv (cross-correlation, zero pad 1) along the strip axis.
// ---------------------------------------------------------------------------
__global__ __launch_bounds__(256) void k_conv3(const float* __restrict__ PH,
                                               const float* __restrict__ PV,
                                               const float* __restrict__ chw,
                                               const float* __restrict__ cvw,
                                               float* __restrict__ XH,
                                               float* __restrict__ XV) {
    const int flat = blockIdx.x * 256 + threadIdx.x;
    const int w    = flat & 255;
    const int o    = (flat >> 8) & 63;
    const int b    = (flat >> 14) & 3;
    const int half = flat >> 16;
    const float* src = half ? PV : PH;
    const float* wt  = half ? cvw : chw;
    float*       dst = half ? XV : XH;
    float acc = 0.f;
    #pragma unroll 8
    for (int c = 0; c < 64; ++c) {
        const float* sp = src + (b * 64 + c) * 256;
        const float* wp = wt + o * 192 + c * 3;
        const float v0 = (w >= 1)   ? sp[w - 1] : 0.f;
        const float v1 = sp[w];
        const float v2 = (w <= 254) ? sp[w + 1] : 0.f;
        acc += wp[0] * v0 + wp[1] * v1 + wp[2] * v2;
    }
    dst[(b * 64 + o) * 256 + w] = acc;
}

// ---------------------------------------------------------------------------
// K3 v2: fused per-pixel-kernel + 3x3 gather + 1x1 GEMM.
//   out[o] = sum_c W[o,c]*z[c] + cb[o]*kin
// Changes vs v1 (latency-bound, 2 blocks/CU, scalar gathers):
//  - phase 1 thread = (channel, 4-px group): 3 aligned float4 loads per row,
//    taps formed by register component selection (loads /4, bytes-per-inst x4)
//  - split-C: zl holds 32 channels -> LDS 37.9KB -> 4 blocks/CU (50% occ)
//  - XCD-chunked block swizzle: halo rows reused within one XCD's L2
// ---------------------------------------------------------------------------
__global__ __launch_bounds__(256, 4) void k_fused(const float* __restrict__ x,
                                                  const float* __restrict__ cw,
                                                  const float* __restrict__ cb,
                                                  const float* __restrict__ XH,
                                                  const float* __restrict__ XV,
                                                  const float* __restrict__ fw,
                                                  const float* __restrict__ fb,
                                                  float* __restrict__ out) {
    __shared__ __align__(16) float zl[32 * 128];      // 16KB  z[c_local][px]
    __shared__ __align__(16) float wt[64 * 64];       // 16KB  wt[c][o] = cw[o][c]
    __shared__ __align__(16) float kernl[10 * 128];   // 5KB   rows 0-8 kern, row 9 kin

    // XCD-chunked bijective swizzle (2048 blocks, 8 XCDs, 256 per chunk):
    // consecutive logical (b,h) tiles land on the same XCD -> halo L2 reuse.
    const int lg   = (blockIdx.x & 7) * 256 + (blockIdx.x >> 3);
    const int half = lg & 1;
    const int h    = (lg >> 1) & 255;                 // uniform in block
    const int b    = lg >> 9;
    const int w0   = half * 128;
    const int tid  = threadIdx.x;

    // stage W^T: wt[c*64+o] = cw[o*64+c]
    #pragma unroll
    for (int r = 0; r < 16; ++r) {
        const int idx = r * 256 + tid;
        wt[idx] = cw[(idx & 63) * 64 + (idx >> 6)];
    }

    // ---- phase 0: per-pixel 9-tap kernel (+kin) from strip features ----
    if (tid < 128) {
        const int w = w0 + tid;
        float k9[9];
        #pragma unroll
        for (int o = 0; o < 9; ++o) k9[o] = fb[o];
        const float* XHb = XH + b * 64 * 256;
        const float* XVb = XV + b * 64 * 256;
        #pragma unroll 8
        for (int c = 0; c < 64; ++c) {
            const float s = XHb[c * 256 + w] + XVb[c * 256 + h];
            const float a = s > 0.f ? s : 0.2f * s;
            #pragma unroll
            for (int o = 0; o < 9; ++o) k9[o] += fw[o * 64 + c] * a;
        }
        float kt[9];
        #pragma unroll
        for (int o = 0; o < 9; ++o) {
            kt[o] = fast_tanh(k9[o]);
            kernl[o * 128 + tid] = kt[o];
        }
        const float m0 = (w >= 1)   ? 1.f : 0.f;
        const float m2 = (w <= 254) ? 1.f : 0.f;
        const float r0 = (h >= 1)   ? 1.f : 0.f;
        const float r2 = (h <= 254) ? 1.f : 0.f;
        float kin = 0.f;
        kin += r0 * (kt[0] * m0 + kt[1] + kt[2] * m2);
        kin +=      (kt[3] * m0 + kt[4] + kt[5] * m2);
        kin += r2 * (kt[6] * m0 + kt[7] + kt[8] * m2);
        kernl[9 * 128 + tid] = kin;
    }
    __syncthreads();

    // ---- phase 1/2 setup ----
    const int g   = tid & 31;                  // px4 group within 128-px strip
    const int c0  = tid >> 5;                  // channel sub-lane (0..7)
    const int gg  = half * 32 + g;             // global float4 column (0..63)
    const int ggL = (gg > 0)  ? gg - 1 : 0;
    const int ggR = (gg < 63) ? gg + 1 : 63;
    const float mL = (gg == 0)  ? 0.f : 1.f;
    const float mR = (gg == 63) ? 0.f : 1.f;
    const bool rv0 = (h > 0);                  // uniform
    const bool rv2 = (h < 255);                // uniform
    const float* xb = x + (size_t)b * 64 * HWp;

    // per-px4 kernel taps: kr[q] = kern row q for this thread's 4 pixels
    float4 kr[9];
    #pragma unroll
    for (int q = 0; q < 9; ++q)
        kr[q] = *reinterpret_cast<const float4*>(&kernl[q * 128 + g * 4]);

    const int og = tid >> 6;                   // wave-uniform output group
    const int po = tid & 63;                   // lane -> 2 pixels
    const int o0 = og * 16;
    float2 acc[16];
    #pragma unroll
    for (int i = 0; i < 16; ++i) acc[i] = make_float2(0.f, 0.f);

    #pragma unroll
    for (int chalf = 0; chalf < 2; ++chalf) {
        // ---- phase 1: z for 32 channels into zl ----
        #pragma unroll
        for (int it = 0; it < 4; ++it) {
            const int cl = it * 8 + c0;        // 0..31
            const int c  = chalf * 32 + cl;
            const float* rowm = xb + (size_t)c * HWp + h * 256;
            float4 z = make_float4(0.f, 0.f, 0.f, 0.f);
            // taps by register component selection; edge masks only at gg 0/63
            #define ROW3(rp, ka, kb_, kc) { \
                const float4 vM = *reinterpret_cast<const float4*>((rp) + gg  * 4); \
                const float4 vL = *reinterpret_cast<const float4*>((rp) + ggL * 4); \
                const float4 vR = *reinterpret_cast<const float4*>((rp) + ggR * 4); \
                const float xl = vL.w * mL; \
                const float xr = vR.x * mR; \
                z.x += (ka).x * xl   + (kb_).x * vM.x + (kc).x * vM.y; \
                z.y += (ka).y * vM.x + (kb_).y * vM.y + (kc).y * vM.z; \
                z.z += (ka).z * vM.y + (kb_).z * vM.z + (kc).z * vM.w; \
                z.w += (ka).w * vM.z + (kb_).w * vM.w + (kc).w * xr;   }
            if (rv0) ROW3(rowm - 256, kr[0], kr[1], kr[2]);
            ROW3(rowm,       kr[3], kr[4], kr[5]);
            if (rv2) ROW3(rowm + 256, kr[6], kr[7], kr[8]);
            #undef ROW3
            *reinterpret_cast<float4*>(&zl[cl * 128 + g * 4]) = z;
        }
        __syncthreads();

        // ---- phase 2: partial GEMM over this c-half ----
        const float* wth = wt + chalf * 32 * 64;
        #pragma unroll 8
        for (int cl = 0; cl < 32; ++cl) {
            const float2 xv = *reinterpret_cast<const float2*>(&zl[cl * 128 + po * 2]);
            const float4 q0 = *reinterpret_cast<const float4*>(&wth[cl * 64 + o0]);
            const float4 q1 = *reinterpret_cast<const float4*>(&wth[cl * 64 + o0 + 4]);
            const float4 q2 = *reinterpret_cast<const float4*>(&wth[cl * 64 + o0 + 8]);
            const float4 q3 = *reinterpret_cast<const float4*>(&wth[cl * 64 + o0 + 12]);
            const float ws[16] = {q0.x, q0.y, q0.z, q0.w, q1.x, q1.y, q1.z, q1.w,
                                  q2.x, q2.y, q2.z, q2.w, q3.x, q3.y, q3.z, q3.w};
            #pragma unroll
            for (int i = 0; i < 16; ++i) {
                acc[i].x += ws[i] * xv.x;
                acc[i].y += ws[i] * xv.y;
            }
        }
        if (chalf == 0) __syncthreads();       // protect zl before overwrite
    }

    // ---- epilogue: + cb[o]*kin, store ----
    const float2 kin2 = *reinterpret_cast<const float2*>(&kernl[9 * 128 + po * 2]);
    float* ob = out + (size_t)b * 64 * HWp + h * 256 + w0;
    #pragma unroll
    for (int i = 0; i < 16; ++i) {
        const float bias = cb[o0 + i];
        float2 r;
        r.x = acc[i].x + bias * kin2.x;
        r.y = acc[i].y + bias * kin2.y;
        *reinterpret_cast<float2*>(ob + (size_t)(o0 + i) * HWp + po * 2) = r;
    }
}

// ---------------------------------------------------------------------------
extern "C" void kernel_launch(void* const* d_in, const int* in_sizes, int n_in,
                              void* d_out, int out_size, void* d_ws, size_t ws_size,
                              hipStream_t stream) {
    const float* x   = (const float*)d_in[0];
    const float* cw  = (const float*)d_in[1];   // (64,64)
    const float* cb  = (const float*)d_in[2];   // (64,)
    const float* chw = (const float*)d_in[3];   // (64,64,1,3)
    const float* cvw = (const float*)d_in[4];   // (64,64,3,1)
    const float* fw  = (const float*)d_in[5];   // (9,64)
    const float* fb  = (const float*)d_in[6];   // (9,)
    float* out = (float*)d_out;

    // workspace (floats): Sh | Sv | PH | PV | XH | XV  (65536 each = 1.5MB)
    float* ws = (float*)d_ws;
    float* Sh  = ws;
    float* Sv  = Sh + 65536;
    float* PH  = Sv + 65536;
    float* PV  = PH + 65536;
    float* XHa = PV + 65536;
    float* XVa = XHa + 65536;

    hipLaunchKernelGGL(k_pool,  dim3(256),  dim3(256), 0, stream, x, Sh, Sv);
    hipLaunchKernelGGL(k_conv1, dim3(512),  dim3(256), 0, stream, Sh, Sv, cw, cb, PH, PV);
    hipLaunchKernelGGL(k_conv3, dim3(512),  dim3(256), 0, stream, PH, PV, chw, cvw, XHa, XVa);
    hipLaunchKernelGGL(k_fused, dim3(2048), dim3(256), 0, stream, x, cw, cb, XHa, XVa, fw, fb, out);
}